// Round 1
// baseline (94.282 us; speedup 1.0000x reference)
//
#include <hip/hip_runtime.h>

// Statevector shape: (2,)*24 + (4,), float32, row-major.
// TARGET qubit = 11 -> element stride = 4 * 2^(23-11) = 16384 floats.
// Total elements = 2^24 * 4 = 67108864.
//
// For each pair (i0, i1 = i0 + 16384):
//   out[i0] = p00*s[i0] + p01*s[i1]
//   out[i1] = p10*s[i0] + p11*s[i1]
//
// Vectorized as float4: stride in float4 units = 4096; pairs4 = 8388608.

__global__ __launch_bounds__(256) void pauli_apply_kernel(
    const float4* __restrict__ state,
    const float* __restrict__ pauli,
    float4* __restrict__ out) {
    const int tid = blockIdx.x * blockDim.x + threadIdx.x;  // [0, 8388608)

    const float p00 = pauli[0];
    const float p01 = pauli[1];
    const float p10 = pauli[2];
    const float p11 = pauli[3];

    // group = tid / 4096 (upper-axis index), within = tid % 4096 (lower axes)
    const int group  = tid >> 12;
    const int within = tid & 4095;
    const int idx0 = (group << 13) + within;  // float4 units
    const int idx1 = idx0 + 4096;

    const float4 s0 = state[idx0];
    const float4 s1 = state[idx1];

    float4 o0, o1;
    o0.x = p00 * s0.x + p01 * s1.x;
    o0.y = p00 * s0.y + p01 * s1.y;
    o0.z = p00 * s0.z + p01 * s1.z;
    o0.w = p00 * s0.w + p01 * s1.w;

    o1.x = p10 * s0.x + p11 * s1.x;
    o1.y = p10 * s0.y + p11 * s1.y;
    o1.z = p10 * s0.z + p11 * s1.z;
    o1.w = p10 * s0.w + p11 * s1.w;

    out[idx0] = o0;
    out[idx1] = o1;
}

extern "C" void kernel_launch(void* const* d_in, const int* in_sizes, int n_in,
                              void* d_out, int out_size, void* d_ws, size_t ws_size,
                              hipStream_t stream) {
    const float4* state = (const float4*)d_in[0];
    const float*  pauli = (const float*)d_in[1];
    float4*       out   = (float4*)d_out;

    // pairs in float4 units: 67108864 / 2 / 4 = 8388608
    const int npairs4 = 8388608;
    const int block = 256;
    const int grid = npairs4 / block;  // 32768

    pauli_apply_kernel<<<grid, block, 0, stream>>>(state, pauli, out);
}

// Round 3
// 91.548 us; speedup vs baseline: 1.0299x; 1.0299x over previous
//
#include <hip/hip_runtime.h>

// Statevector shape: (2,)*24 + (4,), float32, row-major.
// TARGET qubit = 11 -> element stride = 16384 floats = 4096 float4s.
// Total: 2^24 * 4 = 67108864 floats = 16777216 float4s = 8388608 float4-pairs.
//
// out[i0] = p00*s[i0] + p01*s[i1];  out[i1] = p10*s[i0] + p11*s[i1]
//
// Pure streaming (read-once/write-once): non-temporal hints bypass L2
// allocate. Each thread handles 2 pairs (tid and tid + NPAIRS/2) for ILP.
// Use clang ext_vector_type: __builtin_nontemporal_* rejects HIP_vector_type.

typedef float f32x4 __attribute__((ext_vector_type(4)));

#define NPAIRS4 8388608

__global__ __launch_bounds__(256) void pauli_apply_kernel(
    const f32x4* __restrict__ state,
    const float* __restrict__ pauli,
    f32x4* __restrict__ out) {
    const int tid = blockIdx.x * blockDim.x + threadIdx.x;  // [0, NPAIRS4/2)

    const float p00 = pauli[0];
    const float p01 = pauli[1];
    const float p10 = pauli[2];
    const float p11 = pauli[3];

    const int t0 = tid;
    const int t1 = tid + (NPAIRS4 / 2);

    // pair index -> (idx0, idx1) in float4 units
    const int g0 = t0 >> 12, w0 = t0 & 4095;
    const int a0 = (g0 << 13) + w0, b0 = a0 + 4096;
    const int g1 = t1 >> 12, w1 = t1 & 4095;
    const int a1 = (g1 << 13) + w1, b1 = a1 + 4096;

    const f32x4 sA0 = __builtin_nontemporal_load(&state[a0]);
    const f32x4 sB0 = __builtin_nontemporal_load(&state[b0]);
    const f32x4 sA1 = __builtin_nontemporal_load(&state[a1]);
    const f32x4 sB1 = __builtin_nontemporal_load(&state[b1]);

    const f32x4 oA0 = p00 * sA0 + p01 * sB0;
    const f32x4 oB0 = p10 * sA0 + p11 * sB0;
    const f32x4 oA1 = p00 * sA1 + p01 * sB1;
    const f32x4 oB1 = p10 * sA1 + p11 * sB1;

    __builtin_nontemporal_store(oA0, &out[a0]);
    __builtin_nontemporal_store(oB0, &out[b0]);
    __builtin_nontemporal_store(oA1, &out[a1]);
    __builtin_nontemporal_store(oB1, &out[b1]);
}

extern "C" void kernel_launch(void* const* d_in, const int* in_sizes, int n_in,
                              void* d_out, int out_size, void* d_ws, size_t ws_size,
                              hipStream_t stream) {
    const f32x4* state = (const f32x4*)d_in[0];
    const float* pauli = (const float*)d_in[1];
    f32x4*       out   = (f32x4*)d_out;

    const int nthreads = NPAIRS4 / 2;  // 4194304
    const int block = 256;
    const int grid = nthreads / block;  // 16384

    pauli_apply_kernel<<<grid, block, 0, stream>>>(state, pauli, out);
}